// Round 8
// baseline (816.503 us; speedup 1.0000x reference)
//
#include <hip/hip_runtime.h>

// ---------------- types / helpers ----------------
typedef __bf16 bf16x8 __attribute__((ext_vector_type(8)));
typedef float  f32x4  __attribute__((ext_vector_type(4)));
typedef float  f32x16 __attribute__((ext_vector_type(16)));
typedef unsigned int u32;
typedef unsigned int u32x4 __attribute__((ext_vector_type(4)));

#if defined(__has_builtin)
#if __has_builtin(__builtin_amdgcn_exp2f)
#define EXP2F(x) __builtin_amdgcn_exp2f(x)
#else
#define EXP2F(x) exp2f(x)
#endif
#else
#define EXP2F(x) exp2f(x)
#endif

__device__ __forceinline__ void gload16(const void* gptr, void* lptr) {
    // async global -> LDS, 16B per lane; LDS dest is wave-uniform base + lane*16
    __builtin_amdgcn_global_load_lds(
        (__attribute__((address_space(1))) void*)gptr,
        (__attribute__((address_space(3))) void*)lptr,
        16, 0, 0);
}

__device__ __forceinline__ unsigned short bfbits(float f) {
    return __builtin_bit_cast(unsigned short, (__bf16)f);
}
__device__ __forceinline__ float b2f(ushort u) {
    unsigned v = (unsigned)u << 16;
    return __builtin_bit_cast(float, v);
}

// problem constants
#define TT    16384      // total tokens
#define EE    1280
#define E3    3840
#define NH    16
#define HD    80
#define ROT   40
#define SEQL  2048

// ---------------- kernel 1: x fp32 -> bf16 ----------------
__global__ void __launch_bounds__(256) conv_x(const float* __restrict__ in, ushort* __restrict__ out) {
    int i = (blockIdx.x * 256 + threadIdx.x) * 4;
    float4 v = *(const float4*)(in + i);
    ushort4 o = make_ushort4(bfbits(v.x), bfbits(v.y), bfbits(v.z), bfbits(v.w));
    *(ushort4*)(out + i) = o;
}

// ---------------- kernel 2: fp32 [R][C] -> bf16 [C][R] ----------------
__global__ void __launch_bounds__(256) transpose_conv(const float* __restrict__ in, ushort* __restrict__ out,
                                                      int R, int C) {
    __shared__ float sT[64 * 65];
    const int cb = blockIdx.x * 64, rb = blockIdx.y * 64;
    const int tid = threadIdx.x;
    {
        int r = tid >> 2, cg = (tid & 3) * 16;
        const float* src = in + (size_t)(rb + r) * C + cb + cg;
        for (int j = 0; j < 16; j += 4) {
            float4 v = *(const float4*)(src + j);
            sT[r * 65 + cg + j + 0] = v.x;
            sT[r * 65 + cg + j + 1] = v.y;
            sT[r * 65 + cg + j + 2] = v.z;
            sT[r * 65 + cg + j + 3] = v.w;
        }
    }
    __syncthreads();
    {
        int c = tid >> 2, rg = (tid & 3) * 16;
        ushort* dst = out + (size_t)(cb + c) * R + rb + rg;
        for (int j = 0; j < 16; j += 4) {
            ushort4 o = make_ushort4(bfbits(sT[(rg + j + 0) * 65 + c]),
                                     bfbits(sT[(rg + j + 1) * 65 + c]),
                                     bfbits(sT[(rg + j + 2) * 65 + c]),
                                     bfbits(sT[(rg + j + 3) * 65 + c]));
            *(ushort4*)(dst + j) = o;
        }
    }
}

// ---------------- GEMM 256x256 8-phase (T2+T3+T4+T5) ----------------
// C[M][N] = A[M][K=1280] (row stride lda) * Bt[N][K=1280]^T + bias[N]
// 2-phase structure plateaued at ~750 TF across v1/v2/v3b (T2/T4 fixes null —
// regime gate confirmed 3x). This is the 8-phase 256^2 port:
//  - BM=BN=256, BK=64; 512 threads = 8 waves (2M x 4N); per-wave out 128x64.
//  - LDS 128KB: A,B each 2 x (256 rows x 128B). 1 block/CU; ILP not TLP.
//  - Per K-tile t: 4 phases = 4 output quadrants (mh,nh), 16 MFMA each.
//    Each phase stages ONE half-tile of tile t+1 (2 gload16/thread, uniform):
//    p0:A-h0  p1:A-h1  p2:B-h0  p3:B-h1  -> into buf[(t+1)&1].
//  - Waits: every wave needs A-half(wm), B-half(wn>>1) before phase 0, so the
//    ONLY vmcnt is at p0: vmcnt(2) (the 2 loads just issued for t+1 may remain
//    in flight; the 8 loads of tile t are forced to have landed). Tail: vmcnt(0).
//    Phase-0 barrier gives cross-wave visibility; trailing barrier per phase
//    makes the first stage into a freed buffer safe (follows last reader).
//  - LDS rows 128B = 8 chunks: slot = kc ^ (row&7) both-sides swizzle (the v2
//    geometry that MEASURED 0 conflicts): linear gload_lds dest, pre-swizzled
//    per-lane global source, XOR on ds_read. 2 lanes/bank-group = free.
//  - setprio(1) around the MFMA cluster (T5 pays only in phase-split schedules).
template <int OM>
__global__ void __launch_bounds__(512) gemm256(const ushort* __restrict__ A, int lda,
                                               const ushort* __restrict__ Bt,
                                               const float* __restrict__ bias,
                                               void* __restrict__ Cout, int N) {
    __shared__ __align__(16) ushort sA[2][256 * 64];   // 32KB per buffer
    __shared__ __align__(16) ushort sB[2][256 * 64];
    const int m0 = blockIdx.x * 256, n0 = blockIdx.y * 256;
    const int tid = threadIdx.x, wave = tid >> 6, lane = tid & 63;
    const int ln = lane & 15, quad = lane >> 4;
    const int wm = wave >> 2, wn = wave & 3;

    f32x4 acc[8][4];
#pragma unroll
    for (int a = 0; a < 8; a++)
#pragma unroll
        for (int b = 0; b < 4; b++) { acc[a][b][0] = 0.f; acc[a][b][1] = 0.f; acc[a][b][2] = 0.f; acc[a][b][3] = 0.f; }

    // staging precompute: half-tile = 128 rows x 8 chunks = 1024 chunks;
    // thread's chunks c = j*512+tid. Dest is linear (chunk c); source chunk is
    // pre-swizzled: gc = (c&7) ^ (row&7).
    int aoff[2], boff[2], dchunk[2];
#pragma unroll
    for (int j = 0; j < 2; j++) {
        int c = j * 512 + tid;
        int r = c >> 3, gc = (c & 7) ^ (r & 7);
        aoff[j] = (m0 + r) * lda + gc * 8;
        boff[j] = (n0 + r) * 1280 + gc * 8;
        dchunk[j] = j * 512 + wave * 64;           // wave-uniform dest base
    }
    auto stageA = [&](int t, int h) {
        ushort* dst = sA[t & 1];
        const ushort* src = A + (size_t)(h * 128) * lda + t * 64;
#pragma unroll
        for (int j = 0; j < 2; j++)
            gload16(src + aoff[j], (char*)dst + (size_t)(h * 1024 + dchunk[j]) * 16);
    };
    auto stageB = [&](int t, int h) {
        ushort* dst = sB[t & 1];
        const ushort* src = Bt + (size_t)(h * 128) * 1280 + t * 64;
#pragma unroll
        for (int j = 0; j < 2; j++)
            gload16(src + boff[j], (char*)dst + (size_t)(h * 1024 + dchunk[j]) * 16);
    };

    // prologue: all 4 half-tiles of tile 0 (8 loads/thread)
    stageA(0, 0); stageA(0, 1); stageB(0, 0); stageB(0, 1);

    for (int kt = 0; kt < 20; kt++) {
        const char* cA = (const char*)sA[kt & 1];
        const char* cB = (const char*)sB[kt & 1];
        bf16x8 af[4][2];
#pragma unroll
        for (int p = 0; p < 4; p++) {
            // stage one half-tile of tile kt+1 into the other buffer
            if (kt < 19) {
                if (p == 0) stageA(kt + 1, 0);
                else if (p == 1) stageA(kt + 1, 1);
                else if (p == 2) stageB(kt + 1, 0);
                else stageB(kt + 1, 1);
            }
            if (p == 0) {
                if (kt < 19) __asm__ __volatile__("s_waitcnt vmcnt(2)" ::: "memory");
                else         __asm__ __volatile__("s_waitcnt vmcnt(0)" ::: "memory");
            }
            __builtin_amdgcn_s_barrier();

            const int mh = p >> 1, nh = p & 1;
            if (nh == 0) {  // phases 0,2: load this quadrant-row's A frags
#pragma unroll
                for (int i = 0; i < 4; i++) {
                    const char* arow = cA + (size_t)(wm * 128 + (mh * 4 + i) * 16 + ln) * 128;
#pragma unroll
                    for (int ks = 0; ks < 2; ks++)
                        af[i][ks] = *(const bf16x8*)(arow + (((ks * 4 + quad) ^ (ln & 7)) * 16));
                }
            }
            bf16x8 bf[2][2];
#pragma unroll
            for (int n = 0; n < 2; n++) {
                const char* brow = cB + (size_t)(wn * 64 + (nh * 2 + n) * 16 + ln) * 128;
#pragma unroll
                for (int ks = 0; ks < 2; ks++)
                    bf[n][ks] = *(const bf16x8*)(brow + (((ks * 4 + quad) ^ (ln & 7)) * 16));
            }
            __builtin_amdgcn_s_setprio(1);
#pragma unroll
            for (int ks = 0; ks < 2; ks++)
#pragma unroll
                for (int i = 0; i < 4; i++)
#pragma unroll
                    for (int n = 0; n < 2; n++)
                        acc[mh * 4 + i][nh * 2 + n] =
                            __builtin_amdgcn_mfma_f32_16x16x32_bf16(af[i][ks], bf[n][ks],
                                                                    acc[mh * 4 + i][nh * 2 + n], 0, 0, 0);
            __builtin_amdgcn_s_setprio(0);
            __builtin_amdgcn_s_barrier();
        }
    }
    // epilogue: C/D layout col=lane&15, row=quad*4+reg
#pragma unroll
    for (int nt = 0; nt < 4; nt++) {
        int col = n0 + wn * 64 + nt * 16 + ln;
        float bv = bias[col];
#pragma unroll
        for (int mt = 0; mt < 8; mt++) {
            int row0 = m0 + wm * 128 + mt * 16 + quad * 4;
#pragma unroll
            for (int r = 0; r < 4; r++) {
                float v = acc[mt][nt][r] + bv;
                if (OM == 0)
                    ((__bf16*)Cout)[(size_t)(row0 + r) * N + col] = (__bf16)v;
                else
                    ((float*)Cout)[(size_t)(row0 + r) * N + col] = v;
            }
        }
    }
}

// ---------------- kernel: pack V^T per (seq,head): vt[pair][d][2048] ----------------
// MUST run before rope_qk (rope overwrites the V columns with roped K).
__global__ void __launch_bounds__(256) vt_pack(const ushort* __restrict__ qkv, ushort* __restrict__ vt) {
    __shared__ ushort sV[80 * 68];
    const int pair = blockIdx.x, tb = blockIdx.y;
    const int s = pair >> 4, h = pair & 15;
    const int T0 = s * SEQL + tb * 64;
    const int tid = threadIdx.x;
    for (int i = 0; i < 5; i++) {
        int c = i * 256 + tid;        // 1280 ushort4 chunks (64 tok x 20)
        int t = c / 20, d4 = c % 20;
        ushort4 v = *(const ushort4*)(qkv + (size_t)(T0 + t) * E3 + 2560 + h * HD + d4 * 4);
        sV[(d4 * 4 + 0) * 68 + t] = v.x;
        sV[(d4 * 4 + 1) * 68 + t] = v.y;
        sV[(d4 * 4 + 2) * 68 + t] = v.z;
        sV[(d4 * 4 + 3) * 68 + t] = v.w;
    }
    __syncthreads();
    for (int i = 0; i < 5; i++) {
        int c = i * 256 + tid;        // 80 d x 16 chunks
        int d = c >> 4, t4 = c & 15;
        const ushort* row = sV + d * 68 + t4 * 4;
        ushort4 o = make_ushort4(row[0], row[1], row[2], row[3]);
        *(ushort4*)(vt + (size_t)pair * (HD * SEQL) + (size_t)d * SEQL + tb * 64 + t4 * 4) = o;
    }
}

// ---------------- out-of-place RoPE ----------------
// Q: read qkv cols [0,1280)  -> write qpack[pair][tok][80], scaled by log2e/sqrt(80)
// K: read qkv cols [1280,2560) -> write qkv cols [2560,3840) (dead V slot)
__global__ void __launch_bounds__(256) rope_qk(ushort* __restrict__ qkv,
                                               ushort* __restrict__ qpack,
                                               const float* __restrict__ cosg,
                                               const float* __restrict__ sing) {
    const int b0 = blockIdx.x * 4;
    const float kap = 0.16129822f;  // log2(e)/sqrt(80)
    for (int i = 0; i < 5; i++) {
        int task = i * 256 + threadIdx.x;   // [0,1280): token(4) x {Q,K}(2) x head(16) x d4(10)
        int tt   = task / 320;
        int rem  = task - tt * 320;
        int qk   = rem / 160;
        int rem2 = rem - qk * 160;
        int hh   = rem2 / 10;
        int d4   = rem2 - hh * 10;
        int tok  = b0 + tt;
        const ushort* src = qkv + (size_t)tok * E3 + qk * 1280 + hh * HD + d4 * 4;
        ushort4 a = *(const ushort4*)src;
        ushort4 b = *(const ushort4*)(src + ROT);
        const float* cp = cosg + (size_t)tok * ROT + d4 * 4;
        const float* sp = sing + (size_t)tok * ROT + d4 * 4;
        float sc = (qk == 0) ? kap : 1.0f;
        float a4[4] = {b2f(a.x), b2f(a.y), b2f(a.z), b2f(a.w)};
        float b4[4] = {b2f(b.x), b2f(b.y), b2f(b.z), b2f(b.w)};
        ushort oa[4], ob[4];
        for (int j = 0; j < 4; j++) {
            float cc = cp[j], ss = sp[j];
            oa[j] = bfbits((a4[j] * cc - b4[j] * ss) * sc);
            ob[j] = bfbits((b4[j] * cc + a4[j] * ss) * sc);
        }
        ushort* dst;
        if (qk == 0) {
            int pair = (tok >> 11) * 16 + hh;
            dst = qpack + (size_t)pair * (SEQL * HD) + (size_t)(tok & 2047) * HD + d4 * 4;
        } else {
            dst = qkv + (size_t)tok * E3 + 2560 + hh * HD + d4 * 4;
        }
        *(ushort4*)dst       = make_ushort4(oa[0], oa[1], oa[2], oa[3]);
        *(ushort4*)(dst + ROT) = make_ushort4(ob[0], ob[1], ob[2], ob[3]);
    }
}

// ---------------- flash attention (v10: counted-vmcnt schedule) ----------------
// 512 thr, 32x32 MFMA, P-in-reg (permlane32_swap), setprio, counted vmcnt(3).
__global__ void __launch_bounds__(512) attn(const ushort* __restrict__ qpack, ushort* __restrict__ kv,
                                            const ushort* __restrict__ vt) {
    __shared__ __align__(16) char sKb[2][11264];    // K tiles: 64 rows x 176B (160B data + 16B pad)
    __shared__ __align__(16) char sVb[2][13824];    // VT tiles: 96 rows x 144B (80 rows staged)
    // XCD swizzle: 1024 blocks, 8 XCDs -> 128 per XCD; pair = wg>>3 so one pair's
    // 8 qb-blocks are consecutive within an XCD chunk.
    const int L = blockIdx.x;
    const int wg = (L & 7) * 128 + (L >> 3);
    const int pair = wg >> 3, qb = wg & 7;
    const int s = pair >> 4, h = pair & 15;
    const int tid = threadIdx.x, wave = tid >> 6, lane = tid & 63;
    const int l31 = lane & 31, hi = lane >> 5;
    const int T0 = s * SEQL + qb * 256;

    // unified chunk space, 3 rounds x 512 threads = 1536 chunks:
    //   [0,704):    K  (64 rows x 11 chunks; chunk 10 = pad, re-loads row start)
    //   [704,1424): VT (80 rows x 9 chunks; chunk 8 = pad)
    //   [1424,1536): dummy (source = tile row 0; dest = VT scrap rows)
    int offs[3];
#pragma unroll
    for (int i = 0; i < 3; i++) {
        int g = i * 512 + tid;
        if (g < 704) {
            int r = g / 11, c = g - r * 11;
            int cc = (c < 10) ? c : 0;
            offs[i] = r * (E3 * 2) + cc * 16;
        } else {
            int v = g - 704;
            if (v < 720) {
                int d = v / 9, c9 = v - 9 * d;
                int cc = (c9 < 8) ? c9 : 0;
                offs[i] = d * 4096 + cc * 16;
            } else {
                offs[i] = 0;                       // dummy: reload VT row 0 start
            }
        }
    }
    const size_t kbase0 = (size_t)(s * SEQL) * (E3 * 2) + (size_t)(2560 + h * HD) * 2;
    const size_t vbase0 = (size_t)pair * 327680;

    auto stage = [&](int n) {
        const size_t kb = kbase0 + (size_t)n * (64 * E3 * 2);
        const size_t vb = vbase0 + (size_t)n * 128;
        char* kd = sKb[n & 1];
        char* vd = sVb[n & 1];
#pragma unroll
        for (int i = 0; i < 3; i++) {
            int cb = i * 512 + wave * 64;          // wave-uniform
            if (cb < 704) gload16((const char*)kv + kb + offs[i], kd + (size_t)cb * 16);
            else          gload16((const char*)vt + vb + offs[i], vd + (size_t)(cb - 704) * 16);
        }
    };

    // Q fragments direct from global (B-operand 32x32x16: col q = lane&31,
    // k = hi*8+j). Wave owns q rows [wave*32, wave*32+32).
    bf16x8 qf[5];
    {
        const ushort* qr = qpack + (size_t)pair * (SEQL * HD) + (size_t)(qb * 256 + wave * 32 + l31) * HD;
#pragma unroll
        for (int ks = 0; ks < 5; ks++)
            qf[ks] = *(const bf16x8*)(qr + ks * 16 + hi * 8);
    }

    stage(0);
    stage(1);

    f32x16 z16;
#pragma unroll
    for (int j = 0; j < 16; j++) z16[j] = 0.f;
    f32x16 O32[3];
    O32[0] = z16; O32[1] = z16; O32[2] = z16;
    float lpart = 0.f;

    __asm__ __volatile__("s_waitcnt vmcnt(3)" ::: "memory");   // tile 0 (and qf) landed
    __builtin_amdgcn_s_barrier();

    for (int kt = 0; kt < 32; kt++) {
        const char* sK = sKb[kt & 1];
        const char* sVT = sVb[kt & 1];

#pragma unroll
        for (int kvt = 0; kvt < 2; kvt++) {
            // S^T tile: 32 kv x 32 q. A = K (row = kv = lane&31, k = hi*8+j),
            // B = Q (col = q = lane&31). 5 k-steps of 16 cover HD=80 exactly.
            const char* kbase = sK + (size_t)(kvt * 32 + l31) * 176 + hi * 16;
            f32x16 St;
            __builtin_amdgcn_s_setprio(1);
            {
                bf16x8 kf = *(const bf16x8*)(kbase);
                St = __builtin_amdgcn_mfma_f32_32x32x16_bf16(kf, qf[0], z16, 0, 0, 0);
            }
#pragma unroll
            for (int ks = 1; ks < 5; ks++) {
                bf16x8 kf = *(const bf16x8*)(kbase + ks * 32);
                St = __builtin_amdgcn_mfma_f32_32x32x16_bf16(kf, qf[ks], St, 0, 0, 0);
            }
            __builtin_amdgcn_s_setprio(0);
            // softmax-lite (log2 domain; Q pre-scaled by log2e/sqrt(80)).
            // Lane holds P[kv32 = (r&3)+8*(r>>2)+4*hi][q = l31], r in [0,16).
            u32 pk[8];
#pragma unroll
            for (int g = 0; g < 4; g++) {
                float p0 = EXP2F(St[4 * g + 0]);
                float p1 = EXP2F(St[4 * g + 1]);
                float p2 = EXP2F(St[4 * g + 2]);
                float p3 = EXP2F(St[4 * g + 3]);
                lpart += (p0 + p1) + (p2 + p3);
                pk[2 * g + 0] = (u32)bfbits(p0) | ((u32)bfbits(p1) << 16);
                pk[2 * g + 1] = (u32)bfbits(p2) | ((u32)bfbits(p3) << 16);
            }
            // Build PV B-fragments in-register (permlane32_swap; zero DS traffic).
#pragma unroll
            for (int ks16 = 0; ks16 < 2; ks16++) {
                u32 a = pk[4 * ks16 + 0], b = pk[4 * ks16 + 2];
                u32 c = pk[4 * ks16 + 1], d = pk[4 * ks16 + 3];
                asm volatile("v_permlane32_swap_b32 %0, %1" : "+v"(a), "+v"(b));
                asm volatile("v_permlane32_swap_b32 %0, %1" : "+v"(c), "+v"(d));
                u32x4 fw = {a, c, b, d};   // words j01, j23, j45, j67
                bf16x8 pfrag = __builtin_bit_cast(bf16x8, fw);
                const int kvs = kvt * 2 + ks16;
                // O^T += VT(A: row d = lane&31) x P(B: col q = lane&31)
                const char* vrow = sVT + (size_t)l31 * 144 + kvs * 32 + hi * 16;
                __builtin_amdgcn_s_setprio(1);
#pragma unroll
                for (int dt = 0; dt < 3; dt++) {
                    bf16x8 vf = *(const bf16x8*)(vrow + dt * (32 * 144));
                    O32[dt] = __builtin_amdgcn_mfma_f32_32x32x16_bf16(vf, pfrag, O32[dt], 0, 0, 0);
                }
                __builtin_amdgcn_s_setprio(0);
            }
        }
        if (kt < 31) {
            __builtin_amdgcn_s_barrier();          // all waves done reading buf[kt&1]
            if (kt < 30) {
                stage(kt + 2);                      // refill freed buffer
                __asm__ __volatile__("s_waitcnt vmcnt(3)" ::: "memory");  // stage(kt+1) done
            } else {
                __asm__ __volatile__("s_waitcnt vmcnt(0)" ::: "memory");  // tail
            }
            __builtin_amdgcn_s_barrier();          // stage(kt+1) visible to all waves
        }
    }
    // l-sum: lane and its hi-partner hold disjoint kv subsets of the same q.
    float lred = lpart + __shfl_xor(lpart, 32, 64);
    float inv = 1.0f / lred;
    // epilogue: O^T layout col q = l31 (lane-local!), row d = (r&3)+8*(r>>2)+4*hi
    // + 32*dt. Store runs of 4 consecutive d as ushort4. dt=2 valid only r>>2 < 2.
    const int row = T0 + wave * 32 + l31;
    ushort* outp = (ushort*)kv + (size_t)row * E3 + h * HD;
#pragma unroll
    for (int dt = 0; dt < 3; dt++) {
        const int ng = (dt == 2) ? 2 : 4;
#pragma unroll
        for (int g2 = 0; g2 < 4; g2++) {
            if (g2 < ng) {
                ushort4 o = make_ushort4(bfbits(O32[dt][4 * g2 + 0] * inv),
                                         bfbits(O32[dt][4 * g2 + 1] * inv),
                                         bfbits(O32[dt][4 * g2 + 2] * inv),
                                         bfbits(O32[dt][4 * g2 + 3] * inv));
                *(ushort4*)(outp + dt * 32 + g2 * 8 + hi * 4) = o;
            }
        }
    }
}

// ---------------- launch ----------------
extern "C" void kernel_launch(void* const* d_in, const int* in_sizes, int n_in,
                              void* d_out, int out_size, void* d_ws, size_t ws_size,
                              hipStream_t stream) {
    const float* x    = (const float*)d_in[0];
    // d_in[1] = cu_seqlens (unused: fixed 8x2048 tiling per reference)
    const float* cosg = (const float*)d_in[2];
    const float* sing = (const float*)d_in[3];
    const float* Wqkv = (const float*)d_in[4];
    const float* bqkv = (const float*)d_in[5];
    const float* Wout = (const float*)d_in[6];
    const float* bout = (const float*)d_in[7];

    char* ws = (char*)d_ws;
    ushort* xbf   = (ushort*)(ws);                 // 41,943,040 B; dead after gemm1 -> qpack
    ushort* wqkvT = (ushort*)(ws + 41943040);      //  9,830,400 B
    ushort* woutT = (ushort*)(ws + 51773440);      //  3,276,800 B
    ushort* qkvbf = (ushort*)(ws + 55050240);      // 125,829,120 B (Q|K|V cols; V->ropedK; Q->attn out)
    ushort* vtw   = (ushort*)(ws + 180879360);     // 41,943,040 B   (total 222,822,400 B)
    ushort* qpack = xbf;

    conv_x<<<dim3(20480), dim3(256), 0, stream>>>(x, xbf);
    transpose_conv<<<dim3(60, 20), dim3(256), 0, stream>>>(Wqkv, wqkvT, 1280, 3840);
    transpose_conv<<<dim3(20, 20), dim3(256), 0, stream>>>(Wout, woutT, 1280, 1280);
    gemm256<0><<<dim3(64, 15), dim3(512), 0, stream>>>(xbf, 1280, wqkvT, bqkv, (void*)qkvbf, 3840);
    vt_pack<<<dim3(128, 32), dim3(256), 0, stream>>>(qkvbf, vtw);            // consume V first
    rope_qk<<<dim3(4096), dim3(256), 0, stream>>>(qkvbf, qpack, cosg, sing); // Q->qpack, K->V-slot
    attn<<<dim3(1024), dim3(512), 0, stream>>>(qpack, qkvbf, vtw);           // out -> Q-slot
    gemm256<1><<<dim3(64, 5), dim3(512), 0, stream>>>(qkvbf, 3840, woutT, bout, d_out, 1280);
}

// Round 9
// 700.484 us; speedup vs baseline: 1.1656x; 1.1656x over previous
//
#include <hip/hip_runtime.h>

// ---------------- types / helpers ----------------
typedef __bf16 bf16x8 __attribute__((ext_vector_type(8)));
typedef float  f32x4  __attribute__((ext_vector_type(4)));
typedef float  f32x16 __attribute__((ext_vector_type(16)));
typedef unsigned int u32;
typedef unsigned int u32x4 __attribute__((ext_vector_type(4)));

#if defined(__has_builtin)
#if __has_builtin(__builtin_amdgcn_exp2f)
#define EXP2F(x) __builtin_amdgcn_exp2f(x)
#else
#define EXP2F(x) exp2f(x)
#endif
#else
#define EXP2F(x) exp2f(x)
#endif

__device__ __forceinline__ void gload16(const void* gptr, void* lptr) {
    // async global -> LDS, 16B per lane; LDS dest is wave-uniform base + lane*16
    __builtin_amdgcn_global_load_lds(
        (__attribute__((address_space(1))) void*)gptr,
        (__attribute__((address_space(3))) void*)lptr,
        16, 0, 0);
}

__device__ __forceinline__ unsigned short bfbits(float f) {
    return __builtin_bit_cast(unsigned short, (__bf16)f);
}
__device__ __forceinline__ float b2f(ushort u) {
    unsigned v = (unsigned)u << 16;
    return __builtin_bit_cast(float, v);
}

// problem constants
#define TT    16384      // total tokens
#define EE    1280
#define E3    3840
#define NH    16
#define HD    80
#define ROT   40
#define SEQL  2048

// ---------------- kernel 1: x fp32 -> bf16 ----------------
__global__ void __launch_bounds__(256) conv_x(const float* __restrict__ in, ushort* __restrict__ out) {
    int i = (blockIdx.x * 256 + threadIdx.x) * 4;
    float4 v = *(const float4*)(in + i);
    ushort4 o = make_ushort4(bfbits(v.x), bfbits(v.y), bfbits(v.z), bfbits(v.w));
    *(ushort4*)(out + i) = o;
}

// ---------------- kernel 2: fp32 [R][C] -> bf16 [C][R] ----------------
__global__ void __launch_bounds__(256) transpose_conv(const float* __restrict__ in, ushort* __restrict__ out,
                                                      int R, int C) {
    __shared__ float sT[64 * 65];
    const int cb = blockIdx.x * 64, rb = blockIdx.y * 64;
    const int tid = threadIdx.x;
    {
        int r = tid >> 2, cg = (tid & 3) * 16;
        const float* src = in + (size_t)(rb + r) * C + cb + cg;
        for (int j = 0; j < 16; j += 4) {
            float4 v = *(const float4*)(src + j);
            sT[r * 65 + cg + j + 0] = v.x;
            sT[r * 65 + cg + j + 1] = v.y;
            sT[r * 65 + cg + j + 2] = v.z;
            sT[r * 65 + cg + j + 3] = v.w;
        }
    }
    __syncthreads();
    {
        int c = tid >> 2, rg = (tid & 3) * 16;
        ushort* dst = out + (size_t)(cb + c) * R + rb + rg;
        for (int j = 0; j < 16; j += 4) {
            ushort4 o = make_ushort4(bfbits(sT[(rg + j + 0) * 65 + c]),
                                     bfbits(sT[(rg + j + 1) * 65 + c]),
                                     bfbits(sT[(rg + j + 2) * 65 + c]),
                                     bfbits(sT[(rg + j + 3) * 65 + c]));
            *(ushort4*)(dst + j) = o;
        }
    }
}

// ---------------- GEMM v1: the measured-best 2-phase structure (214us gemm1) ----
// C[M][N] = A[M][K=1280] (row stride lda) * Bt[N][K=1280]^T + bias[N]
// Session record: v2 (BK=64+swizzle, 233), v3b (counted vmcnt, 235), 8-phase
// 256^2 ports (264) ALL regressed vs this plain 2-phase BK=32 at 214us (~752 TF
// = the m97-structure ceiling for K=1280). Restored verbatim from round 4.
template <int OM>
__global__ void __launch_bounds__(256) gemm_bt(const ushort* __restrict__ A, int lda,
                                               const ushort* __restrict__ Bt,
                                               const float* __restrict__ bias, void* __restrict__ Cout, int N) {
    __shared__ __align__(16) ushort sA[128 * 32];
    __shared__ __align__(16) ushort sB[128 * 32];
    const int m0 = blockIdx.x * 128, n0 = blockIdx.y * 128;
    const int tid = threadIdx.x, wave = tid >> 6, lane = tid & 63;
    const int ln = lane & 15, quad = lane >> 4;
    const int wm = wave >> 1, wn = wave & 1;

    f32x4 acc[4][4];
    for (int a = 0; a < 4; a++)
        for (int b = 0; b < 4; b++) { acc[a][b][0] = 0.f; acc[a][b][1] = 0.f; acc[a][b][2] = 0.f; acc[a][b][3] = 0.f; }

    const int c0 = tid, c1 = tid + 256;
    const ushort* gA0 = A + (size_t)(m0 + (c0 >> 2)) * lda + (c0 & 3) * 8;
    const ushort* gA1 = A + (size_t)(m0 + (c1 >> 2)) * lda + (c1 & 3) * 8;
    const ushort* gB0 = Bt + (size_t)(n0 + (c0 >> 2)) * 1280 + (c0 & 3) * 8;
    const ushort* gB1 = Bt + (size_t)(n0 + (c1 >> 2)) * 1280 + (c1 & 3) * 8;
    char* lA0 = (char*)sA + (size_t)(wave * 64) * 16;
    char* lA1 = (char*)sA + (size_t)(256 + wave * 64) * 16;
    char* lB0 = (char*)sB + (size_t)(wave * 64) * 16;
    char* lB1 = (char*)sB + (size_t)(256 + wave * 64) * 16;

    for (int kt = 0; kt < 40; kt++) {
        __syncthreads();
        gload16(gA0 + kt * 32, lA0);
        gload16(gA1 + kt * 32, lA1);
        gload16(gB0 + kt * 32, lB0);
        gload16(gB1 + kt * 32, lB1);
        __syncthreads();
        bf16x8 af[4];
        for (int mt = 0; mt < 4; mt++)
            af[mt] = *(const bf16x8*)((const char*)sA + (size_t)(wm * 64 + mt * 16 + ln) * 64 + quad * 16);
        for (int nt = 0; nt < 4; nt++) {
            bf16x8 bfv = *(const bf16x8*)((const char*)sB + (size_t)(wn * 64 + nt * 16 + ln) * 64 + quad * 16);
            for (int mt = 0; mt < 4; mt++)
                acc[mt][nt] = __builtin_amdgcn_mfma_f32_16x16x32_bf16(af[mt], bfv, acc[mt][nt], 0, 0, 0);
        }
    }
    // epilogue: C/D layout col=lane&15, row=quad*4+reg
    for (int nt = 0; nt < 4; nt++) {
        int col = n0 + wn * 64 + nt * 16 + ln;
        float bv = bias[col];
        for (int mt = 0; mt < 4; mt++) {
            int row0 = m0 + wm * 64 + mt * 16 + quad * 4;
            for (int r = 0; r < 4; r++) {
                float v = acc[mt][nt][r] + bv;
                if (OM == 0)
                    ((__bf16*)Cout)[(size_t)(row0 + r) * N + col] = (__bf16)v;
                else
                    ((float*)Cout)[(size_t)(row0 + r) * N + col] = v;
            }
        }
    }
}

// ---------------- kernel: pack V^T per (seq,head): vt[pair][d][2048] ----------------
// MUST run before rope_qk (rope overwrites the V columns with roped K).
__global__ void __launch_bounds__(256) vt_pack(const ushort* __restrict__ qkv, ushort* __restrict__ vt) {
    __shared__ ushort sV[80 * 68];
    const int pair = blockIdx.x, tb = blockIdx.y;
    const int s = pair >> 4, h = pair & 15;
    const int T0 = s * SEQL + tb * 64;
    const int tid = threadIdx.x;
    for (int i = 0; i < 5; i++) {
        int c = i * 256 + tid;        // 1280 ushort4 chunks (64 tok x 20)
        int t = c / 20, d4 = c % 20;
        ushort4 v = *(const ushort4*)(qkv + (size_t)(T0 + t) * E3 + 2560 + h * HD + d4 * 4);
        sV[(d4 * 4 + 0) * 68 + t] = v.x;
        sV[(d4 * 4 + 1) * 68 + t] = v.y;
        sV[(d4 * 4 + 2) * 68 + t] = v.z;
        sV[(d4 * 4 + 3) * 68 + t] = v.w;
    }
    __syncthreads();
    for (int i = 0; i < 5; i++) {
        int c = i * 256 + tid;        // 80 d x 16 chunks
        int d = c >> 4, t4 = c & 15;
        const ushort* row = sV + d * 68 + t4 * 4;
        ushort4 o = make_ushort4(row[0], row[1], row[2], row[3]);
        *(ushort4*)(vt + (size_t)pair * (HD * SEQL) + (size_t)d * SEQL + tb * 64 + t4 * 4) = o;
    }
}

// ---------------- out-of-place RoPE ----------------
// Q: read qkv cols [0,1280)  -> write qpack[pair][tok][80], scaled by log2e/sqrt(80)
// K: read qkv cols [1280,2560) -> write qkv cols [2560,3840) (dead V slot)
__global__ void __launch_bounds__(256) rope_qk(ushort* __restrict__ qkv,
                                               ushort* __restrict__ qpack,
                                               const float* __restrict__ cosg,
                                               const float* __restrict__ sing) {
    const int b0 = blockIdx.x * 4;
    const float kap = 0.16129822f;  // log2(e)/sqrt(80)
    for (int i = 0; i < 5; i++) {
        int task = i * 256 + threadIdx.x;   // [0,1280): token(4) x {Q,K}(2) x head(16) x d4(10)
        int tt   = task / 320;
        int rem  = task - tt * 320;
        int qk   = rem / 160;
        int rem2 = rem - qk * 160;
        int hh   = rem2 / 10;
        int d4   = rem2 - hh * 10;
        int tok  = b0 + tt;
        const ushort* src = qkv + (size_t)tok * E3 + qk * 1280 + hh * HD + d4 * 4;
        ushort4 a = *(const ushort4*)src;
        ushort4 b = *(const ushort4*)(src + ROT);
        const float* cp = cosg + (size_t)tok * ROT + d4 * 4;
        const float* sp = sing + (size_t)tok * ROT + d4 * 4;
        float sc = (qk == 0) ? kap : 1.0f;
        float a4[4] = {b2f(a.x), b2f(a.y), b2f(a.z), b2f(a.w)};
        float b4[4] = {b2f(b.x), b2f(b.y), b2f(b.z), b2f(b.w)};
        ushort oa[4], ob[4];
        for (int j = 0; j < 4; j++) {
            float cc = cp[j], ss = sp[j];
            oa[j] = bfbits((a4[j] * cc - b4[j] * ss) * sc);
            ob[j] = bfbits((b4[j] * cc + a4[j] * ss) * sc);
        }
        ushort* dst;
        if (qk == 0) {
            int pair = (tok >> 11) * 16 + hh;
            dst = qpack + (size_t)pair * (SEQL * HD) + (size_t)(tok & 2047) * HD + d4 * 4;
        } else {
            dst = qkv + (size_t)tok * E3 + 2560 + hh * HD + d4 * 4;
        }
        *(ushort4*)dst       = make_ushort4(oa[0], oa[1], oa[2], oa[3]);
        *(ushort4*)(dst + ROT) = make_ushort4(ob[0], ob[1], ob[2], ob[3]);
    }
}

// ---------------- flash attention (v9: 512 threads, 256 q/block) ----------------
// The round-4 measured-best attn (<213us; total 709.9us). 8 waves/block, 256 q
// rows/block, grid 1024; LDS 50176 B -> 3 blocks/CU, up to 24 resident waves/CU.
// 32x32 MFMA, swapped QK^T (P lane-local), P -> PV B-fragments in registers via
// v_permlane32_swap (zero DS traffic for P), s_setprio around MFMA clusters,
// stage-ahead double-buffer with one end-of-iter __syncthreads.
__global__ void __launch_bounds__(512) attn(const ushort* __restrict__ qpack, ushort* __restrict__ kv,
                                            const ushort* __restrict__ vt) {
    __shared__ __align__(16) char sKb[2][11264];    // K tiles: 64 rows x 176B (160B data + 16B pad)
    __shared__ __align__(16) char sVb[2][13824];    // VT tiles: 96 rows x 144B (80 rows staged)
    // XCD swizzle: 1024 blocks, 8 XCDs -> 128 per XCD; pair = wg>>3 so one pair's
    // 8 qb-blocks are consecutive within an XCD chunk.
    const int L = blockIdx.x;
    const int wg = (L & 7) * 128 + (L >> 3);
    const int pair = wg >> 3, qb = wg & 7;
    const int s = pair >> 4, h = pair & 15;
    const int tid = threadIdx.x, wave = tid >> 6, lane = tid & 63;
    const int l31 = lane & 31, hi = lane >> 5;
    const int T0 = s * SEQL + qb * 256;

    // per-lane tile-relative byte offsets (kt-invariant), 512 threads x 2 rounds
    // K chunk space: 64 rows x 11 chunks (chunk 10 = pad, re-loads row start)
    // VT chunk space: 80 rows x 9 chunks (chunk 8 = pad)
    int koffs[2], voffs[2];
#pragma unroll
    for (int i = 0; i < 2; i++) {
        int g = i * 512 + tid;
        { int r = g / 11, c = g - r * 11; int cc = (c < 10) ? c : 0; koffs[i] = (g < 704) ? (r * (E3 * 2) + cc * 16) : 0; }
        { int d = g / 9,  c9 = g - 9 * d; int cc = (c9 < 8) ? c9 : 0; voffs[i] = (g < 720) ? (d * 4096 + cc * 16) : 0; }
    }
    const size_t kbase0 = (size_t)(s * SEQL) * (E3 * 2) + (size_t)(2560 + h * HD) * 2;
    const size_t vbase0 = (size_t)pair * 327680;

    auto stage_k = [&](int n) {
        const size_t kb = kbase0 + (size_t)n * (64 * E3 * 2);
        char* kd = sKb[n & 1];
#pragma unroll
        for (int i = 0; i < 2; i++) {
            int g = i * 512 + tid;
            int cb = i * 512 + wave * 64;          // wave-uniform chunk base (704 wave-aligned)
            if (g < 704) gload16((const char*)kv + kb + koffs[i], kd + (size_t)cb * 16);
        }
    };
    auto stage_vt = [&](int n) {
        const size_t vb = vbase0 + (size_t)n * 128;
        char* vd = sVb[n & 1];
#pragma unroll
        for (int i = 0; i < 2; i++) {
            int g = i * 512 + tid;
            int cb = i * 512 + wave * 64;          // partial wave at 720 ok (exec-masked)
            if (g < 720) gload16((const char*)vt + vb + voffs[i], vd + (size_t)cb * 16);
        }
    };

    stage_k(0);
    stage_vt(0);

    // Q fragments direct from global (B-operand 32x32x16: col q = lane&31,
    // k = hi*8+j). Wave owns q rows [wave*32, wave*32+32).
    bf16x8 qf[5];
    {
        const ushort* qr = qpack + (size_t)pair * (SEQL * HD) + (size_t)(qb * 256 + wave * 32 + l31) * HD;
#pragma unroll
        for (int ks = 0; ks < 5; ks++)
            qf[ks] = *(const bf16x8*)(qr + ks * 16 + hi * 8);
    }

    f32x16 z16;
#pragma unroll
    for (int j = 0; j < 16; j++) z16[j] = 0.f;
    f32x16 O32[3];
    O32[0] = z16; O32[1] = z16; O32[2] = z16;
    float lpart = 0.f;

    __syncthreads();                // tile 0 staged (barrier drains vmcnt)

    for (int kt = 0; kt < 32; kt++) {
        // prefetch next tile into the other buffers (those were last read in iter
        // kt-1; all waves crossed the end-of-(kt-1) barrier)
        if (kt < 31) { stage_vt(kt + 1); stage_k(kt + 1); }
        const char* sK = sKb[kt & 1];
        const char* sVT = sVb[kt & 1];

#pragma unroll
        for (int kvt = 0; kvt < 2; kvt++) {
            // S^T tile: 32 kv x 32 q. A = K (row = kv = lane&31, k = hi*8+j),
            // B = Q (col = q = lane&31). 5 k-steps of 16 cover HD=80 exactly.
            const char* kbase = sK + (size_t)(kvt * 32 + l31) * 176 + hi * 16;
            f32x16 St;
            __builtin_amdgcn_s_setprio(1);
            {
                bf16x8 kf = *(const bf16x8*)(kbase);
                St = __builtin_amdgcn_mfma_f32_32x32x16_bf16(kf, qf[0], z16, 0, 0, 0);
            }
#pragma unroll
            for (int ks = 1; ks < 5; ks++) {
                bf16x8 kf = *(const bf16x8*)(kbase + ks * 32);
                St = __builtin_amdgcn_mfma_f32_32x32x16_bf16(kf, qf[ks], St, 0, 0, 0);
            }
            __builtin_amdgcn_s_setprio(0);
            // softmax-lite (log2 domain; Q pre-scaled by log2e/sqrt(80)).
            // Lane holds P[kv32 = (r&3)+8*(r>>2)+4*hi][q = l31], r in [0,16).
            // Pack to bf16 pairs: pk[2g+w] = (p[4g+2w], p[4g+2w+1]), g = r>>2.
            u32 pk[8];
#pragma unroll
            for (int g = 0; g < 4; g++) {
                float p0 = EXP2F(St[4 * g + 0]);
                float p1 = EXP2F(St[4 * g + 1]);
                float p2 = EXP2F(St[4 * g + 2]);
                float p3 = EXP2F(St[4 * g + 3]);
                lpart += (p0 + p1) + (p2 + p3);
                pk[2 * g + 0] = (u32)bfbits(p0) | ((u32)bfbits(p1) << 16);
                pk[2 * g + 1] = (u32)bfbits(p2) | ((u32)bfbits(p3) << 16);
            }
            // Build PV B-fragments in-register. For k-step ks16 (kv 16-half of
            // this 32-tile): frag j needs reg group g = 2*ks16 + hi_target from
            // lane-half hi_src = j>>2. One permlane32_swap of (pk[g0], pk[g1])
            // yields both frag words: after swap a = w(j0..1|j4..5 lo), b = w(hi).
#pragma unroll
            for (int ks16 = 0; ks16 < 2; ks16++) {
                u32 a = pk[4 * ks16 + 0], b = pk[4 * ks16 + 2];
                u32 c = pk[4 * ks16 + 1], d = pk[4 * ks16 + 3];
                asm volatile("v_permlane32_swap_b32 %0, %1" : "+v"(a), "+v"(b));
                asm volatile("v_permlane32_swap_b32 %0, %1" : "+v"(c), "+v"(d));
                u32x4 fw = {a, c, b, d};   // words j01, j23, j45, j67
                bf16x8 pfrag = __builtin_bit_cast(bf16x8, fw);
                const int kvs = kvt * 2 + ks16;
                // O^T += VT(A: row d = lane&31) x P(B: col q = lane&31)
                const char* vrow = sVT + (size_t)l31 * 144 + kvs * 32 + hi * 16;
                __builtin_amdgcn_s_setprio(1);
#pragma unroll
                for (int dt = 0; dt < 3; dt++) {
                    bf16x8 vf = *(const bf16x8*)(vrow + dt * (32 * 144));
                    O32[dt] = __builtin_amdgcn_mfma_f32_32x32x16_bf16(vf, pfrag, O32[dt], 0, 0, 0);
                }
                __builtin_amdgcn_s_setprio(0);
            }
        }
        // end-of-iter barrier: all waves done reading tiles kt; stage(kt+1)
        // drained by the barrier's implicit vmcnt(0) -> visible to all waves.
        __syncthreads();
    }
    // l-sum: lane and its hi-partner hold disjoint kv subsets of the same q.
    float lred = lpart + __shfl_xor(lpart, 32, 64);
    float inv = 1.0f / lred;
    // epilogue: O^T layout col q = l31 (lane-local!), row d = (r&3)+8*(r>>2)+4*hi
    // + 32*dt. Store runs of 4 consecutive d as ushort4. dt=2 valid only r>>2 < 2.
    const int row = T0 + wave * 32 + l31;
    ushort* outp = (ushort*)kv + (size_t)row * E3 + h * HD;
#pragma unroll
    for (int dt = 0; dt < 3; dt++) {
        const int ng = (dt == 2) ? 2 : 4;
#pragma unroll
        for (int g2 = 0; g2 < 4; g2++) {
            if (g2 < ng) {
                ushort4 o = make_ushort4(bfbits(O32[dt][4 * g2 + 0] * inv),
                                         bfbits(O32[dt][4 * g2 + 1] * inv),
                                         bfbits(O32[dt][4 * g2 + 2] * inv),
                                         bfbits(O32[dt][4 * g2 + 3] * inv));
                *(ushort4*)(outp + dt * 32 + g2 * 8 + hi * 4) = o;
            }
        }
    }
}

// ---------------- launch ----------------
extern "C" void kernel_launch(void* const* d_in, const int* in_sizes, int n_in,
                              void* d_out, int out_size, void* d_ws, size_t ws_size,
                              hipStream_t stream) {
    const float* x    = (const float*)d_in[0];
    // d_in[1] = cu_seqlens (unused: fixed 8x2048 tiling per reference)
    const float* cosg = (const float*)d_in[2];
    const float* sing = (const float*)d_in[3];
    const float* Wqkv = (const float*)d_in[4];
    const float* bqkv = (const float*)d_in[5];
    const float* Wout = (const float*)d_in[6];
    const float* bout = (const float*)d_in[7];

    char* ws = (char*)d_ws;
    ushort* xbf   = (ushort*)(ws);                 // 41,943,040 B; dead after gemm1 -> qpack
    ushort* wqkvT = (ushort*)(ws + 41943040);      //  9,830,400 B
    ushort* woutT = (ushort*)(ws + 51773440);      //  3,276,800 B
    ushort* qkvbf = (ushort*)(ws + 55050240);      // 125,829,120 B (Q|K|V cols; V->ropedK; Q->attn out)
    ushort* vtw   = (ushort*)(ws + 180879360);     // 41,943,040 B   (total 222,822,400 B)
    ushort* qpack = xbf;

    conv_x<<<dim3(20480), dim3(256), 0, stream>>>(x, xbf);
    transpose_conv<<<dim3(60, 20), dim3(256), 0, stream>>>(Wqkv, wqkvT, 1280, 3840);
    transpose_conv<<<dim3(20, 20), dim3(256), 0, stream>>>(Wout, woutT, 1280, 1280);
    gemm_bt<0><<<dim3(128, 30), dim3(256), 0, stream>>>(xbf, 1280, wqkvT, bqkv, (void*)qkvbf, 3840);
    vt_pack<<<dim3(128, 32), dim3(256), 0, stream>>>(qkvbf, vtw);            // consume V first
    rope_qk<<<dim3(4096), dim3(256), 0, stream>>>(qkvbf, qpack, cosg, sing); // Q->qpack, K->V-slot
    attn<<<dim3(1024), dim3(512), 0, stream>>>(qpack, qkvbf, vtw);           // out -> Q-slot
    gemm_bt<1><<<dim3(128, 10), dim3(256), 0, stream>>>(qkvbf, 3840, woutT, bout, d_out, 1280);
}